// Round 2
// baseline (274.733 us; speedup 1.0000x reference)
//
#include <hip/hip_runtime.h>

#define N_PTS  (4*1024*1024)
#define NCLUST 65536

// ---------------------------------------------------------------------------
// Kernel 0: zero-fill pooled (graph-capture-safe; ws is poisoned 0xAA).
// ---------------------------------------------------------------------------
__global__ __launch_bounds__(256) void k_zero(float4* __restrict__ p)
{
    p[(size_t)blockIdx.x * 256 + threadIdx.x] = make_float4(0.f, 0.f, 0.f, 0.f);
}

// ---------------------------------------------------------------------------
// Kernel 1: per-point fc0 (3->64) + ReLU, fused with sorted segment-max pool.
// Block = 256 threads = 4 waves; each wave serially owns 256 contiguous points
// (all 64 lanes process the same point; lane = feature index 0..63).
// pooled must be zero-initialized (ReLU>=0 makes 0 the identity AND the
// empty-cluster fill value, matching the reference's isfinite->0 fixup).
// NOTE: harness delivers integer inputs as int32 (NOT int64) — read as int*.
// ---------------------------------------------------------------------------
__global__ __launch_bounds__(256) void k_fc0_pool(
        const float* __restrict__ pts,          // [N,3]
        const int* __restrict__ clus,           // [N] sorted, < NCLUST (int32!)
        const float* __restrict__ W0,           // [3,64]
        const float* __restrict__ b0,           // [64]
        float* __restrict__ pooled)             // [NCLUST,64], pre-zeroed
{
    __shared__ float4 Pts[1024];   // xyz + pad -> single ds_read_b128/point
    __shared__ int    Cs[1024];

    const int tid  = threadIdx.x;
    const long long base = (long long)blockIdx.x * 1024;

    // cooperative stage: 1024 points (3072 floats) + 1024 cluster ids
    float* PtsF = (float*)Pts;
    for (int j = tid; j < 3072; j += 256) {
        float v = pts[base * 3 + j];
        PtsF[(j / 3) * 4 + (j % 3)] = v;
    }
    for (int j = tid; j < 1024; j += 256)
        Cs[j] = clus[base + j];
    __syncthreads();

    const int lane = tid & 63;
    const int w    = tid >> 6;              // wave id 0..3
    const float w0x = W0[lane];
    const float w0y = W0[64 + lane];
    const float w0z = W0[128 + lane];
    const float bb  = b0[lane];

    unsigned* pool_u = (unsigned*)pooled;

    int   cur  = __builtin_amdgcn_readfirstlane(Cs[w * 256]);
    float vmax = 0.0f;

    #pragma unroll 4
    for (int i = 0; i < 256; ++i) {
        const int idx = w * 256 + i;
        const int c = __builtin_amdgcn_readfirstlane(Cs[idx]);
        if (c != cur) {                      // uniform (scalar) branch
            atomicMax(&pool_u[(size_t)cur * 64 + lane], __float_as_uint(vmax));
            vmax = 0.0f;
            cur  = c;
        }
        const float4 p = Pts[idx];           // LDS broadcast read
        const float h = fmaf(p.x, w0x, fmaf(p.y, w0y, fmaf(p.z, w0z, bb)));
        vmax = fmaxf(vmax, h);               // ReLU folded: vmax >= 0 invariant
    }
    atomicMax(&pool_u[(size_t)cur * 64 + lane], __float_as_uint(vmax));
}

// ---------------------------------------------------------------------------
// Kernel 2: fc1  pooled[C,64] @ W1[64,128] + b1, ReLU -> h1[C,128]
// Block = 256 thr, tile 32 rows x 128 cols, thread = 4 rows x 4 cols.
// W1 staged in LDS (32 KB), pooled rows in LDS (8 KB).
// ---------------------------------------------------------------------------
__global__ __launch_bounds__(256) void k_fc1(
        const float* __restrict__ pooled,
        const float* __restrict__ W1,
        const float* __restrict__ b1,
        float* __restrict__ h1)
{
    __shared__ float W1s[64 * 128];
    __shared__ float Ps[32 * 64];

    const int tid = threadIdx.x;
    const int r0  = blockIdx.x * 32;

    {
        const float4* src = (const float4*)W1;
        float4* dst = (float4*)W1s;
        #pragma unroll
        for (int j = 0; j < 8; ++j) dst[tid + 256 * j] = src[tid + 256 * j];
        const float4* ps = (const float4*)(pooled + (size_t)r0 * 64);
        float4* pd = (float4*)Ps;
        pd[tid] = ps[tid];
        pd[tid + 256] = ps[tid + 256];
    }
    __syncthreads();

    const int cq = tid & 31;    // col quad: cols [cq*4, cq*4+4)
    const int rq = tid >> 5;    // row quad: rows [rq*4, rq*4+4)

    const float4 bv = ((const float4*)b1)[cq];
    float acc[4][4];
    #pragma unroll
    for (int r = 0; r < 4; ++r) {
        acc[r][0] = bv.x; acc[r][1] = bv.y; acc[r][2] = bv.z; acc[r][3] = bv.w;
    }

    const float4* W1s4 = (const float4*)W1s;  // [64][32]
    const float4* Ps4  = (const float4*)Ps;   // [32][16]

    #pragma unroll
    for (int k4 = 0; k4 < 16; ++k4) {
        float4 wv[4], pv[4];
        #pragma unroll
        for (int kk = 0; kk < 4; ++kk) wv[kk] = W1s4[(k4 * 4 + kk) * 32 + cq];
        #pragma unroll
        for (int rr = 0; rr < 4; ++rr) pv[rr] = Ps4[(rq * 4 + rr) * 16 + k4];
        #pragma unroll
        for (int rr = 0; rr < 4; ++rr) {
            const float* p = (const float*)&pv[rr];
            #pragma unroll
            for (int kk = 0; kk < 4; ++kk) {
                const float* wq = (const float*)&wv[kk];
                acc[rr][0] = fmaf(p[kk], wq[0], acc[rr][0]);
                acc[rr][1] = fmaf(p[kk], wq[1], acc[rr][1]);
                acc[rr][2] = fmaf(p[kk], wq[2], acc[rr][2]);
                acc[rr][3] = fmaf(p[kk], wq[3], acc[rr][3]);
            }
        }
    }

    float4* out4 = (float4*)h1;
    #pragma unroll
    for (int rr = 0; rr < 4; ++rr) {
        const int r = r0 + rq * 4 + rr;
        float4 o;
        o.x = fmaxf(acc[rr][0], 0.0f);
        o.y = fmaxf(acc[rr][1], 0.0f);
        o.z = fmaxf(acc[rr][2], 0.0f);
        o.w = fmaxf(acc[rr][3], 0.0f);
        out4[(size_t)r * 32 + cq] = o;
    }
}

// ---------------------------------------------------------------------------
// Kernel 3: fc2  h1[C,128] @ W2[128,256] + b2, ReLU -> out[C,256]
// Block = 256 thr, tile 32 rows x 256 cols, thread = 8 rows x 4 cols.
// h1 rows in LDS (16 KB); W2 (128 KB) streamed from L2 (high reuse).
// ---------------------------------------------------------------------------
__global__ __launch_bounds__(256) void k_fc2(
        const float* __restrict__ h1,
        const float* __restrict__ W2,
        const float* __restrict__ b2,
        float* __restrict__ out)
{
    __shared__ float Hs[32 * 128];

    const int tid = threadIdx.x;
    const int r0  = blockIdx.x * 32;

    {
        const float4* src = (const float4*)(h1 + (size_t)r0 * 128);
        float4* dst = (float4*)Hs;
        #pragma unroll
        for (int j = 0; j < 4; ++j) dst[tid + 256 * j] = src[tid + 256 * j];
    }
    __syncthreads();

    const int cq = tid & 63;    // col quad: cols [cq*4, cq*4+4)
    const int rg = tid >> 6;    // row group: rows [rg*8, rg*8+8)

    const float4 bv = ((const float4*)b2)[cq];
    float acc[8][4];
    #pragma unroll
    for (int r = 0; r < 8; ++r) {
        acc[r][0] = bv.x; acc[r][1] = bv.y; acc[r][2] = bv.z; acc[r][3] = bv.w;
    }

    const float4* W2g = (const float4*)W2;   // [128][64]
    const float4* Hs4 = (const float4*)Hs;   // [32][32]

    #pragma unroll 2
    for (int k4 = 0; k4 < 32; ++k4) {
        float4 wv[4];
        #pragma unroll
        for (int kk = 0; kk < 4; ++kk) wv[kk] = W2g[(k4 * 4 + kk) * 64 + cq];
        float4 hv[8];
        #pragma unroll
        for (int rr = 0; rr < 8; ++rr) hv[rr] = Hs4[(rg * 8 + rr) * 32 + k4];
        #pragma unroll
        for (int rr = 0; rr < 8; ++rr) {
            const float* h = (const float*)&hv[rr];
            #pragma unroll
            for (int kk = 0; kk < 4; ++kk) {
                const float* wq = (const float*)&wv[kk];
                acc[rr][0] = fmaf(h[kk], wq[0], acc[rr][0]);
                acc[rr][1] = fmaf(h[kk], wq[1], acc[rr][1]);
                acc[rr][2] = fmaf(h[kk], wq[2], acc[rr][2]);
                acc[rr][3] = fmaf(h[kk], wq[3], acc[rr][3]);
            }
        }
    }

    float4* out4 = (float4*)out;
    #pragma unroll
    for (int rr = 0; rr < 8; ++rr) {
        const int r = r0 + rg * 8 + rr;
        float4 o;
        o.x = fmaxf(acc[rr][0], 0.0f);
        o.y = fmaxf(acc[rr][1], 0.0f);
        o.z = fmaxf(acc[rr][2], 0.0f);
        o.w = fmaxf(acc[rr][3], 0.0f);
        out4[(size_t)r * 64 + cq] = o;
    }
}

// ---------------------------------------------------------------------------
extern "C" void kernel_launch(void* const* d_in, const int* in_sizes, int n_in,
                              void* d_out, int out_size, void* d_ws, size_t ws_size,
                              hipStream_t stream) {
    const float* points  = (const float*)d_in[0];
    const int*   cluster = (const int*)d_in[1];   // int32 on device (harness)
    const float* W0      = (const float*)d_in[2];
    const float* b0      = (const float*)d_in[3];
    const float* W1      = (const float*)d_in[4];
    const float* b1      = (const float*)d_in[5];
    const float* W2      = (const float*)d_in[6];
    const float* b2      = (const float*)d_in[7];
    float* out = (float*)d_out;

    float* pooled = (float*)d_ws;                                      // 16 MB
    float* h1     = (float*)((char*)d_ws + (size_t)NCLUST * 64 * 4);   // 32 MB

    // pooled must start at 0 (ws is re-poisoned to 0xAA before every launch)
    k_zero<<<(NCLUST * 64 / 4) / 256, 256, 0, stream>>>((float4*)pooled);

    k_fc0_pool<<<N_PTS / 1024, 256, 0, stream>>>(points, cluster, W0, b0, pooled);
    k_fc1<<<NCLUST / 32, 256, 0, stream>>>(pooled, W1, b1, h1);
    k_fc2<<<NCLUST / 32, 256, 0, stream>>>(h1, W2, b2, out);
}

// Round 3
// 263.916 us; speedup vs baseline: 1.0410x; 1.0410x over previous
//
#include <hip/hip_runtime.h>

#define N_PTS  (4*1024*1024)
#define NCLUST 65536

// ---------------------------------------------------------------------------
// Kernel 0: zero-fill pooled (ws is re-poisoned 0xAA before every launch).
// ---------------------------------------------------------------------------
__global__ __launch_bounds__(256) void k_zero(float4* __restrict__ p)
{
    p[(size_t)blockIdx.x * 256 + threadIdx.x] = make_float4(0.f, 0.f, 0.f, 0.f);
}

// ---------------------------------------------------------------------------
// Kernel 1: per-point fc0 (3->64) + ReLU, fused with sorted segment-max pool.
// Wave = 64 lanes = 64 features; each wave serially owns 256 contiguous
// points, processed in 8-point chunks. Sorted ids => chunk is single-run iff
// first==last==cur (2 scalar checks amortize the per-point id handling).
// pooled pre-zeroed: ReLU>=0 makes 0 both the max-identity and the
// empty-cluster fill (matches reference isfinite->0 fixup).
// ---------------------------------------------------------------------------
__global__ __launch_bounds__(256) void k_fc0_pool(
        const float* __restrict__ pts,          // [N,3]
        const int* __restrict__ clus,           // [N] sorted int32, < NCLUST
        const float* __restrict__ W0,           // [3,64]
        const float* __restrict__ b0,           // [64]
        float* __restrict__ pooled)             // [NCLUST,64], pre-zeroed
{
    __shared__ float4 Pts[1024];   // xyz+pad -> one ds_read_b128 per point
    __shared__ int    Cs[1024];

    const int tid = threadIdx.x;
    const long long base = (long long)blockIdx.x * 1024;

    float* PtsF = (float*)Pts;
    for (int j = tid; j < 3072; j += 256) {
        float v = pts[base * 3 + j];
        PtsF[(j / 3) * 4 + (j % 3)] = v;
    }
    for (int j = tid; j < 1024; j += 256)
        Cs[j] = clus[base + j];
    __syncthreads();

    const int lane = tid & 63;
    const int w    = tid >> 6;
    const float w0x = W0[lane];
    const float w0y = W0[64 + lane];
    const float w0z = W0[128 + lane];
    const float bb  = b0[lane];

    unsigned* pool_u = (unsigned*)pooled;

    int   cur  = __builtin_amdgcn_readfirstlane(Cs[w * 256]);
    float vmax = 0.0f;

    #pragma unroll 1
    for (int i = 0; i < 256; i += 8) {
        const int idx = w * 256 + i;
        const int cf = __builtin_amdgcn_readfirstlane(Cs[idx]);
        const int cl = __builtin_amdgcn_readfirstlane(Cs[idx + 7]);
        if ((cf == cur) & (cl == cur)) {
            // fast path: whole chunk belongs to run `cur`
            const float4 p0 = Pts[idx + 0];
            const float4 p1 = Pts[idx + 1];
            const float4 p2 = Pts[idx + 2];
            const float4 p3 = Pts[idx + 3];
            const float4 p4 = Pts[idx + 4];
            const float4 p5 = Pts[idx + 5];
            const float4 p6 = Pts[idx + 6];
            const float4 p7 = Pts[idx + 7];
            const float h0 = fmaf(p0.x, w0x, fmaf(p0.y, w0y, fmaf(p0.z, w0z, bb)));
            const float h1 = fmaf(p1.x, w0x, fmaf(p1.y, w0y, fmaf(p1.z, w0z, bb)));
            const float h2 = fmaf(p2.x, w0x, fmaf(p2.y, w0y, fmaf(p2.z, w0z, bb)));
            const float h3 = fmaf(p3.x, w0x, fmaf(p3.y, w0y, fmaf(p3.z, w0z, bb)));
            const float h4 = fmaf(p4.x, w0x, fmaf(p4.y, w0y, fmaf(p4.z, w0z, bb)));
            const float h5 = fmaf(p5.x, w0x, fmaf(p5.y, w0y, fmaf(p5.z, w0z, bb)));
            const float h6 = fmaf(p6.x, w0x, fmaf(p6.y, w0y, fmaf(p6.z, w0z, bb)));
            const float h7 = fmaf(p7.x, w0x, fmaf(p7.y, w0y, fmaf(p7.z, w0z, bb)));
            const float m0 = fmaxf(fmaxf(h0, h1), fmaxf(h2, h3));
            const float m1 = fmaxf(fmaxf(h4, h5), fmaxf(h6, h7));
            vmax = fmaxf(vmax, fmaxf(m0, m1));
        } else {
            // boundary chunk: per-point walk (rare: ~12% of chunks)
            #pragma unroll 1
            for (int t = 0; t < 8; ++t) {
                const int c = __builtin_amdgcn_readfirstlane(Cs[idx + t]);
                if (c != cur) {              // uniform scalar branch
                    atomicMax(&pool_u[(size_t)cur * 64 + lane], __float_as_uint(vmax));
                    vmax = 0.0f;
                    cur  = c;
                }
                const float4 p = Pts[idx + t];
                const float h = fmaf(p.x, w0x, fmaf(p.y, w0y, fmaf(p.z, w0z, bb)));
                vmax = fmaxf(vmax, h);
            }
        }
    }
    atomicMax(&pool_u[(size_t)cur * 64 + lane], __float_as_uint(vmax));
}

// ---------------------------------------------------------------------------
// Kernel 2: fused fc1+fc2.  Per block: 32 cluster rows.
//   Phase A: h1[32,128] = relu(Ps[32,64] @ W1[64,128] + b1)   (-> LDS Hs)
//   Phase B: out[32,256] = relu(Hs @ W2[128,256] + b2)
// Ps (8 KB) + W1 (32 KB) + Hs (16.5 KB, 128->132 pad: phase-A writes
// conflict-free, phase-B reads broadcast) = 57 KB LDS -> 2 blocks/CU.
// W2 (128 KB) streamed from L2 (resident; L1 absorbs row-group redundancy).
// ---------------------------------------------------------------------------
__global__ __launch_bounds__(256) void k_mlp(
        const float* __restrict__ pooled,
        const float* __restrict__ W1,
        const float* __restrict__ b1,
        const float* __restrict__ W2,
        const float* __restrict__ b2,
        float* __restrict__ out)
{
    __shared__ float Ps[32 * 64];
    __shared__ float W1s[64 * 128];
    __shared__ float Hs[32 * 132];

    const int tid = threadIdx.x;
    const int r0b = blockIdx.x * 32;

    {   // stage Ps + W1s
        const float4* ps = (const float4*)(pooled + (size_t)r0b * 64);
        float4* pd = (float4*)Ps;
        pd[tid]       = ps[tid];
        pd[tid + 256] = ps[tid + 256];
        const float4* ws = (const float4*)W1;
        float4* wd = (float4*)W1s;
        #pragma unroll
        for (int j = 0; j < 8; ++j) wd[tid + 256 * j] = ws[tid + 256 * j];
    }
    __syncthreads();

    // ---------------- Phase A: fc1 -> Hs ----------------
    {
        const int cq = tid & 31;    // cols cq*4..+4
        const int rq = tid >> 5;    // rows rq*4..+4
        const float4 bv = ((const float4*)b1)[cq];
        float acc[4][4];
        #pragma unroll
        for (int r = 0; r < 4; ++r) {
            acc[r][0] = bv.x; acc[r][1] = bv.y; acc[r][2] = bv.z; acc[r][3] = bv.w;
        }
        const float4* W1s4 = (const float4*)W1s;  // [64][32]
        const float4* Ps4  = (const float4*)Ps;   // [32][16]
        #pragma unroll
        for (int k4 = 0; k4 < 16; ++k4) {
            float4 wv[4], pv[4];
            #pragma unroll
            for (int kk = 0; kk < 4; ++kk) wv[kk] = W1s4[(k4 * 4 + kk) * 32 + cq];
            #pragma unroll
            for (int rr = 0; rr < 4; ++rr) pv[rr] = Ps4[(rq * 4 + rr) * 16 + k4];
            #pragma unroll
            for (int rr = 0; rr < 4; ++rr) {
                const float* p = (const float*)&pv[rr];
                #pragma unroll
                for (int kk = 0; kk < 4; ++kk) {
                    const float* wq = (const float*)&wv[kk];
                    acc[rr][0] = fmaf(p[kk], wq[0], acc[rr][0]);
                    acc[rr][1] = fmaf(p[kk], wq[1], acc[rr][1]);
                    acc[rr][2] = fmaf(p[kk], wq[2], acc[rr][2]);
                    acc[rr][3] = fmaf(p[kk], wq[3], acc[rr][3]);
                }
            }
        }
        #pragma unroll
        for (int rr = 0; rr < 4; ++rr) {
            float4 o;
            o.x = fmaxf(acc[rr][0], 0.0f);
            o.y = fmaxf(acc[rr][1], 0.0f);
            o.z = fmaxf(acc[rr][2], 0.0f);
            o.w = fmaxf(acc[rr][3], 0.0f);
            *(float4*)&Hs[(rq * 4 + rr) * 132 + cq * 4] = o;
        }
    }
    __syncthreads();

    // ---------------- Phase B: fc2 -> out ----------------
    {
        const int cg = tid & 31;    // cols cg*4 and cg*4+128
        const int rg = tid >> 5;    // rows rg*4..+4
        const float4 bv0 = ((const float4*)b2)[cg];
        const float4 bv1 = ((const float4*)b2)[cg + 32];
        float acc0[4][4], acc1[4][4];
        #pragma unroll
        for (int r = 0; r < 4; ++r) {
            acc0[r][0] = bv0.x; acc0[r][1] = bv0.y; acc0[r][2] = bv0.z; acc0[r][3] = bv0.w;
            acc1[r][0] = bv1.x; acc1[r][1] = bv1.y; acc1[r][2] = bv1.z; acc1[r][3] = bv1.w;
        }
        const float4* W2g = (const float4*)W2;    // [128][64]
        #pragma unroll 2
        for (int k4 = 0; k4 < 32; ++k4) {
            float4 hv[4];
            #pragma unroll
            for (int rr = 0; rr < 4; ++rr)
                hv[rr] = *(const float4*)&Hs[(rg * 4 + rr) * 132 + k4 * 4];
            #pragma unroll
            for (int kk = 0; kk < 4; ++kk) {
                const float4 w0 = W2g[(k4 * 4 + kk) * 64 + cg];
                const float4 w1 = W2g[(k4 * 4 + kk) * 64 + 32 + cg];
                #pragma unroll
                for (int rr = 0; rr < 4; ++rr) {
                    const float hk = ((const float*)&hv[rr])[kk];
                    acc0[rr][0] = fmaf(hk, w0.x, acc0[rr][0]);
                    acc0[rr][1] = fmaf(hk, w0.y, acc0[rr][1]);
                    acc0[rr][2] = fmaf(hk, w0.z, acc0[rr][2]);
                    acc0[rr][3] = fmaf(hk, w0.w, acc0[rr][3]);
                    acc1[rr][0] = fmaf(hk, w1.x, acc1[rr][0]);
                    acc1[rr][1] = fmaf(hk, w1.y, acc1[rr][1]);
                    acc1[rr][2] = fmaf(hk, w1.z, acc1[rr][2]);
                    acc1[rr][3] = fmaf(hk, w1.w, acc1[rr][3]);
                }
            }
        }
        float4* out4 = (float4*)out;
        #pragma unroll
        for (int rr = 0; rr < 4; ++rr) {
            const int r = r0b + rg * 4 + rr;
            float4 o0, o1;
            o0.x = fmaxf(acc0[rr][0], 0.0f);
            o0.y = fmaxf(acc0[rr][1], 0.0f);
            o0.z = fmaxf(acc0[rr][2], 0.0f);
            o0.w = fmaxf(acc0[rr][3], 0.0f);
            o1.x = fmaxf(acc1[rr][0], 0.0f);
            o1.y = fmaxf(acc1[rr][1], 0.0f);
            o1.z = fmaxf(acc1[rr][2], 0.0f);
            o1.w = fmaxf(acc1[rr][3], 0.0f);
            out4[(size_t)r * 64 + cg]      = o0;
            out4[(size_t)r * 64 + 32 + cg] = o1;
        }
    }
}

// ---------------------------------------------------------------------------
extern "C" void kernel_launch(void* const* d_in, const int* in_sizes, int n_in,
                              void* d_out, int out_size, void* d_ws, size_t ws_size,
                              hipStream_t stream) {
    const float* points  = (const float*)d_in[0];
    const int*   cluster = (const int*)d_in[1];   // int32 on device (harness)
    const float* W0      = (const float*)d_in[2];
    const float* b0      = (const float*)d_in[3];
    const float* W1      = (const float*)d_in[4];
    const float* b1      = (const float*)d_in[5];
    const float* W2      = (const float*)d_in[6];
    const float* b2      = (const float*)d_in[7];
    float* out = (float*)d_out;

    float* pooled = (float*)d_ws;   // 16 MB

    k_zero<<<(NCLUST * 64 / 4) / 256, 256, 0, stream>>>((float4*)pooled);
    k_fc0_pool<<<N_PTS / 1024, 256, 0, stream>>>(points, cluster, W0, b0, pooled);
    k_mlp<<<NCLUST / 32, 256, 0, stream>>>(pooled, W1, b1, W2, b2, out);
}